// Round 12
// baseline (1084.768 us; speedup 1.0000x reference)
//
#include <hip/hip_runtime.h>

typedef _Float16 f16x8 __attribute__((ext_vector_type(8)));
typedef _Float16 f16x4 __attribute__((ext_vector_type(4)));
typedef float f32x4 __attribute__((ext_vector_type(4)));

#define TT 512
#define BB 128
#define II 512
#define HH 512
#define NBLK 32   // phase-2 blocks; 4 batch rows each

__device__ __forceinline__ f16x8 cvt8(f32x4 a, f32x4 b) {
  f16x8 r;
  r[0] = (_Float16)a[0]; r[1] = (_Float16)a[1];
  r[2] = (_Float16)a[2]; r[3] = (_Float16)a[3];
  r[4] = (_Float16)b[0]; r[5] = (_Float16)b[1];
  r[6] = (_Float16)b[2]; r[7] = (_Float16)b[3];
  return r;
}

// ============================ FAST PATH (ws >= 64 MB) ============================
// Phase 1: xw = x @ W_ih^T + b, fp16, BLOCK-MAJOR layout [T][NBLK][H][4]
// (element ((t*32+blk)*512+h)*4 + b_local, blk = batch>>2): each phase-2
// block's per-step slab is 4 KB contiguous (fixed FETCH 270->45 MB in r7).
__global__ __launch_bounds__(256) void xw_gemm_f16(
    const float* __restrict__ X, const float* __restrict__ Wih,
    const float* __restrict__ bias, _Float16* __restrict__ out) {
  __shared__ _Float16 As[128][40];
  __shared__ _Float16 Bs[128][40];
  const int tid = threadIdx.x;
  const int lane = tid & 63, wv = tid >> 6;
  const int l15 = lane & 15, lhi = lane >> 4;
  const int ntile = blockIdx.x & 3;
  const int mtile = blockIdx.x >> 2;   // == timestep t
  const int M0 = mtile * 128, N0 = ntile * 128;
  const int wm = (wv & 1) * 64, wn = (wv >> 1) * 64;

  f32x4 acc[4][4];
#pragma unroll
  for (int ni = 0; ni < 4; ++ni) {
    const float bv = bias[N0 + wn + ni * 16 + l15];
#pragma unroll
    for (int mi = 0; mi < 4; ++mi) {
      acc[mi][ni][0] = bv; acc[mi][ni][1] = bv;
      acc[mi][ni][2] = bv; acc[mi][ni][3] = bv;
    }
  }
  const int srow = tid >> 1;
  const int shalf = (tid & 1) * 16;

  for (int k0 = 0; k0 < II; k0 += 32) {
    const float* ax = X + (size_t)(M0 + srow) * II + k0 + shalf;
    const float* bx = Wih + (size_t)(N0 + srow) * II + k0 + shalf;
    f32x4 a0 = *(const f32x4*)ax,       a1 = *(const f32x4*)(ax + 4);
    f32x4 a2 = *(const f32x4*)(ax + 8), a3 = *(const f32x4*)(ax + 12);
    f32x4 b0 = *(const f32x4*)bx,       b1 = *(const f32x4*)(bx + 4);
    f32x4 b2 = *(const f32x4*)(bx + 8), b3 = *(const f32x4*)(bx + 12);
    *(f16x8*)&As[srow][shalf]     = cvt8(a0, a1);
    *(f16x8*)&As[srow][shalf + 8] = cvt8(a2, a3);
    *(f16x8*)&Bs[srow][shalf]     = cvt8(b0, b1);
    *(f16x8*)&Bs[srow][shalf + 8] = cvt8(b2, b3);
    __syncthreads();
    f16x8 af[4], bf[4];
#pragma unroll
    for (int mi = 0; mi < 4; ++mi) af[mi] = *(const f16x8*)&As[wm + mi * 16 + l15][lhi * 8];
#pragma unroll
    for (int ni = 0; ni < 4; ++ni) bf[ni] = *(const f16x8*)&Bs[wn + ni * 16 + l15][lhi * 8];
#pragma unroll
    for (int mi = 0; mi < 4; ++mi)
#pragma unroll
      for (int ni = 0; ni < 4; ++ni)
        acc[mi][ni] = __builtin_amdgcn_mfma_f32_16x16x32_f16(af[mi], bf[ni], acc[mi][ni], 0, 0, 0);
    __syncthreads();
  }
  // epilogue: block-major fp16. bb is 4-aligned -> b_local == 0 always.
#pragma unroll
  for (int mi = 0; mi < 4; ++mi)
#pragma unroll
    for (int ni = 0; ni < 4; ++ni) {
      const int n = N0 + wn + ni * 16 + l15;
      const int bb = wm + mi * 16 + lhi * 4;
      f16x4 hv;
      hv[0] = (_Float16)acc[mi][ni][0]; hv[1] = (_Float16)acc[mi][ni][1];
      hv[2] = (_Float16)acc[mi][ni][2]; hv[3] = (_Float16)acc[mi][ni][3];
      *(f16x4*)&out[(((size_t)mtile * NBLK + (bb >> 2)) * HH + n) * 4] = hv;
    }
}

// Phase 2: h_t = tanh(xw_t + h_{t-1} @ W_hh^T), ROW-REPLICATED MFMA.
// 32 blocks x 4 batch rows, 512 threads = 8 waves (2/SIMD), wave owns 64 cols.
// r12 change vs r11: W-LDS layout re-keyed to the READ pattern:
//   W[row][k] stored at  kj*32768 + row*64 + slot*16   (kj = (k-384)>>5,
//   slot = ((k-384)>>3)&3). A bf read instruction (fixed kj, ni) then has
//   lane (l15,lhi) at base + l15*64 + lhi*16 -> the wave's 64 lanes cover ONE
//   CONTIGUOUS 1 KB block (stride-1-optimal, m134) -> bf conflicts eliminated
//   (r11 halved conflicts via the af rotation; the remaining 8.4M was bf).
// h buffers: rotation swizzle (r11-proven). W split (r8-proven): k<384 ->
// 48 reg frags; k>=384 -> 128 KB LDS. One barrier/step, direct nt stores.
__global__ __launch_bounds__(512, 2) void rnn_rec_f16(
    const float* __restrict__ Whh,
    const _Float16* __restrict__ xw,
    float* __restrict__ hout) {
  __shared__ char lds[139264];
  char* wbase = lds;            // [4 kj][512 rows][4 slots][16 B] = 128 KB
  char* hb0 = lds + 131072;     // h buffer A: [4 rows][1024 B] fp16, rotation swz
  char* hb1 = lds + 135168;     // h buffer B
  const int tid = threadIdx.x;
  const int lane = tid & 63, wv = tid >> 6;   // wv 0..7
  const int l15 = lane & 15, lhi = lane >> 4;
  const int blk = blockIdx.x;                 // 0..31
  const int row0 = blk * 4;                   // batch rows [row0, row0+4)
  const int col0 = wv * 64;
  const int mycol = col0 + lhi * 16 + l15;    // this lane's output column

  // ---- stage W k-chunk [384,512) into read-ordered LDS (fp32 -> fp16) ----
#pragma unroll
  for (int i = 0; i < 16; ++i) {
    const int u = i * 512 + tid;   // 0..8191 = 512 rows x 16 k-octets
    const int r = u >> 4;
    const int oct = u & 15;        // k-local octet: k = 384 + oct*8 .. +8
    const float* src = Whh + (size_t)r * HH + 384 + oct * 8;
    *(f16x8*)(wbase + (oct >> 2) * 32768 + r * 64 + (oct & 3) * 16) =
        cvt8(*(const f32x4*)src, *(const f32x4*)(src + 4));
  }
  // ---- zero h buffer A rows 0..3 (h_{-1} = 0; any layout, all-zero) ----
  for (int i = tid; i < 1024; i += 512) ((unsigned int*)hb0)[i] = 0u;

  // ---- W register fragments, k in [0,384) ----
  f16x8 wreg[48];
#pragma unroll
  for (int ni = 0; ni < 4; ++ni) {
    const float* wr = Whh + (size_t)(col0 + ni * 16 + l15) * HH + lhi * 8;
#pragma unroll
    for (int kj = 0; kj < 12; ++kj) {
      const float* s = wr + kj * 32;
      wreg[ni * 12 + kj] = cvt8(*(const f32x4*)s, *(const f32x4*)(s + 4));
    }
  }

  // ---- first xw prefetch (t = 0): ONE f16x4 per lane (its own column) ----
  f16x4 pref = *(const f16x4*)&xw[((size_t)blk * HH + mycol) * 4];
  __syncthreads();

  const int arow = l15 & 3;                 // replicated A row this lane reads
  const int arot = arow * 32;               // rotation offset within row
  const int wcol2 = mycol * 2;              // byte col in h row

  for (int t = 0; t < TT; ++t) {
    char* rb = (t & 1) ? hb1 : hb0;   // read h_{t-1}
    char* wb = (t & 1) ? hb0 : hb1;   // write h_t
    f32x4 acc[4];
#pragma unroll
    for (int ni = 0; ni < 4; ++ni) {
      acc[ni][0] = 0.0f; acc[ni][1] = 0.0f; acc[ni][2] = 0.0f; acc[ni][3] = 0.0f;
    }
    const f16x4 myxw = pref;
    // prefetch xw[t+1] under this step's MFMAs
    if (t + 1 < TT) {
      const size_t base = ((size_t)(t + 1) * NBLK + blk) * HH;
      pref = *(const f16x4*)&xw[(base + mycol) * 4];
    }
    // ---- h @ W^T: 12 register k-frags + 4 LDS k-frags ----
#pragma unroll
    for (int kj = 0; kj < 16; ++kj) {
      f16x8 af = *(const f16x8*)(rb + arow * 1024 + ((kj * 64 + lhi * 16 + arot) & 1023));
      if (kj < 12) {
#pragma unroll
        for (int ni = 0; ni < 4; ++ni)
          acc[ni] = __builtin_amdgcn_mfma_f32_16x16x32_f16(af, wreg[ni * 12 + kj], acc[ni], 0, 0, 0);
      } else {
#pragma unroll
        for (int ni = 0; ni < 4; ++ni) {
          // contiguous 1 KB per instruction: lane addr = base + l15*64 + lhi*16
          f16x8 bf = *(const f16x8*)(wbase + (kj - 12) * 32768 +
                        (col0 + ni * 16 + l15) * 64 + lhi * 16);
          acc[ni] = __builtin_amdgcn_mfma_f32_16x16x32_f16(af, bf, acc[ni], 0, 0, 0);
        }
      }
    }
    // ---- tanh on ni == lhi (4 values/lane) -> LDS h_t + DIRECT global store
    float th4[4];
#pragma unroll
    for (int r = 0; r < 4; ++r) {
      const float s = (lhi == 0) ? acc[0][r]
                    : (lhi == 1) ? acc[1][r]
                    : (lhi == 2) ? acc[2][r]
                    :              acc[3][r];
      const float v = s + (float)myxw[r];
      const float xc = fminf(fmaxf(v, -4.97f), 4.97f);
      const float x2 = xc * xc;
      const float p = fmaf(x2, fmaf(x2, fmaf(x2, 1.0f, 378.0f), 17325.0f), 135135.0f) * xc;
      const float q = fmaf(x2, fmaf(x2, fmaf(x2, 28.0f, 3150.0f), 62370.0f), 135135.0f);
      const float th = p * __builtin_amdgcn_rcpf(q);
      th4[r] = th;
      *(_Float16*)(wb + r * 1024 + ((wcol2 + r * 32) & 1023)) = (_Float16)th;
    }
    // coalesced direct stores: per r, wave's 64 lanes cover 64 consecutive cols
    {
      float* dst = hout + (size_t)t * (BB * HH) + (size_t)row0 * HH + mycol;
#pragma unroll
      for (int r = 0; r < 4; ++r)
        __builtin_nontemporal_store(th4[r], dst + (size_t)r * HH);
      if (t == TT - 1) {
        float* fdst = hout + (size_t)TT * (BB * HH) + (size_t)row0 * HH + mycol;
#pragma unroll
        for (int r = 0; r < 4; ++r)
          __builtin_nontemporal_store(th4[r], fdst + (size_t)r * HH);
      }
    }
    // single barrier per step (lgkm-only drain; globals stay in flight)
    asm volatile("s_waitcnt lgkmcnt(0)" ::: "memory");
    __builtin_amdgcn_s_barrier();
    __builtin_amdgcn_sched_barrier(0);
  }
}

// ====================== FALLBACK (ws too small; round-3/5 validated path) ======================
__global__ __launch_bounds__(256) void xw_gemm_f32(
    const float* __restrict__ X, const float* __restrict__ Wih,
    const float* __restrict__ bias, float* __restrict__ out) {
  __shared__ _Float16 As[128][40];
  __shared__ _Float16 Bs[128][40];
  const int tid = threadIdx.x;
  const int lane = tid & 63, wv = tid >> 6;
  const int l15 = lane & 15, lhi = lane >> 4;
  const int ntile = blockIdx.x & 3;
  const int mtile = blockIdx.x >> 2;
  const int M0 = mtile * 128, N0 = ntile * 128;
  const int wm = (wv & 1) * 64, wn = (wv >> 1) * 64;
  f32x4 acc[4][4];
#pragma unroll
  for (int ni = 0; ni < 4; ++ni) {
    const float bv = bias[N0 + wn + ni * 16 + l15];
#pragma unroll
    for (int mi = 0; mi < 4; ++mi) {
      acc[mi][ni][0] = bv; acc[mi][ni][1] = bv;
      acc[mi][ni][2] = bv; acc[mi][ni][3] = bv;
    }
  }
  const int srow = tid >> 1;
  const int shalf = (tid & 1) * 16;
  for (int k0 = 0; k0 < II; k0 += 32) {
    const float* ax = X + (size_t)(M0 + srow) * II + k0 + shalf;
    const float* bx = Wih + (size_t)(N0 + srow) * II + k0 + shalf;
    f32x4 a0 = *(const f32x4*)ax,       a1 = *(const f32x4*)(ax + 4);
    f32x4 a2 = *(const f32x4*)(ax + 8), a3 = *(const f32x4*)(ax + 12);
    f32x4 b0 = *(const f32x4*)bx,       b1 = *(const f32x4*)(bx + 4);
    f32x4 b2 = *(const f32x4*)(bx + 8), b3 = *(const f32x4*)(bx + 12);
    *(f16x8*)&As[srow][shalf]     = cvt8(a0, a1);
    *(f16x8*)&As[srow][shalf + 8] = cvt8(a2, a3);
    *(f16x8*)&Bs[srow][shalf]     = cvt8(b0, b1);
    *(f16x8*)&Bs[srow][shalf + 8] = cvt8(b2, b3);
    __syncthreads();
    f16x8 af[4], bf[4];
#pragma unroll
    for (int mi = 0; mi < 4; ++mi) af[mi] = *(const f16x8*)&As[wm + mi * 16 + l15][lhi * 8];
#pragma unroll
    for (int ni = 0; ni < 4; ++ni) bf[ni] = *(const f16x8*)&Bs[wn + ni * 16 + l15][lhi * 8];
#pragma unroll
    for (int mi = 0; mi < 4; ++mi)
#pragma unroll
      for (int ni = 0; ni < 4; ++ni)
        acc[mi][ni] = __builtin_amdgcn_mfma_f32_16x16x32_f16(af[mi], bf[ni], acc[mi][ni], 0, 0, 0);
    __syncthreads();
  }
#pragma unroll
  for (int mi = 0; mi < 4; ++mi)
#pragma unroll
    for (int ni = 0; ni < 4; ++ni) {
      const size_t rbase = (size_t)(M0 + wm + mi * 16 + lhi * 4) * HH + N0 + wn + ni * 16 + l15;
#pragma unroll
      for (int r = 0; r < 4; ++r) out[rbase + (size_t)r * HH] = acc[mi][ni][r];
    }
}

__global__ __launch_bounds__(512, 2) void rnn_rec_f32(
    const float* __restrict__ Whh,
    const float* __restrict__ xw,
    float* __restrict__ hout) {
  __shared__ char lds[163840];
  char* wbase = lds;
  char* hb0 = lds + 131072;
  char* hb1 = lds + 147456;
  const int tid = threadIdx.x;
  const int lane = tid & 63, wv = tid >> 6;
  const int l15 = lane & 15, lhi = lane >> 4;
  const int row0 = blockIdx.x * 16;
  const int col0 = wv * 64;
#pragma unroll
  for (int i = 0; i < 16; ++i) {
    const int u = i * 512 + tid;
    const int r = u >> 4;
    const int slot = u & 15;
    const float* src = Whh + (size_t)r * HH + 384 + slot * 8;
    *(f16x8*)(wbase + r * 256 + ((slot * 16) ^ ((r & 7) << 4))) =
        cvt8(*(const f32x4*)src, *(const f32x4*)(src + 4));
  }
  for (int i = tid; i < 4096; i += 512) ((unsigned int*)hb0)[i] = 0u;
  f16x8 wreg[48];
#pragma unroll
  for (int ni = 0; ni < 4; ++ni) {
    const float* wr = Whh + (size_t)(col0 + ni * 16 + l15) * HH + lhi * 8;
#pragma unroll
    for (int kj = 0; kj < 12; ++kj) {
      const float* s = wr + kj * 32;
      wreg[ni * 12 + kj] = cvt8(*(const f32x4*)s, *(const f32x4*)(s + 4));
    }
  }
  f32x4 pref[4];
  {
    const size_t base0 = (size_t)(row0 + lhi * 4) * HH + col0 + l15;
#pragma unroll
    for (int ni = 0; ni < 4; ++ni)
#pragma unroll
      for (int r = 0; r < 4; ++r)
        pref[ni][r] = xw[base0 + (size_t)r * HH + ni * 16];
  }
  __syncthreads();
  const int fa = ((l15 & 7) ^ ((l15 >> 3) << 1)) << 4;
  for (int t = 0; t < TT; ++t) {
    char* rb = (t & 1) ? hb1 : hb0;
    char* wb = (t & 1) ? hb0 : hb1;
    f32x4 acc[4];
#pragma unroll
    for (int ni = 0; ni < 4; ++ni) acc[ni] = pref[ni];
    if (t + 1 < TT) {
      const size_t base = (size_t)(t + 1) * (BB * HH) + (size_t)(row0 + lhi * 4) * HH + col0 + l15;
#pragma unroll
      for (int ni = 0; ni < 4; ++ni)
#pragma unroll
        for (int r = 0; r < 4; ++r)
          pref[ni][r] = xw[base + (size_t)r * HH + ni * 16];
    }
#pragma unroll
    for (int kj = 0; kj < 12; ++kj) {
      f16x8 af = *(const f16x8*)(rb + l15 * 1024 + ((kj * 64 + lhi * 16) ^ fa));
#pragma unroll
      for (int ni = 0; ni < 4; ++ni)
        acc[ni] = __builtin_amdgcn_mfma_f32_16x16x32_f16(af, wreg[ni * 12 + kj], acc[ni], 0, 0, 0);
    }
#pragma unroll
    for (int kj = 12; kj < 16; ++kj) {
      f16x8 af = *(const f16x8*)(rb + l15 * 1024 + ((kj * 64 + lhi * 16) ^ fa));
#pragma unroll
      for (int ni = 0; ni < 4; ++ni) {
        const int wrow = col0 + ni * 16 + l15;
        f16x8 bf = *(const f16x8*)(wbase + wrow * 256 +
                      ((((kj - 12) * 32 + lhi * 8) * 2) ^ ((wrow & 7) << 4)));
        acc[ni] = __builtin_amdgcn_mfma_f32_16x16x32_f16(af, bf, acc[ni], 0, 0, 0);
      }
    }
#pragma unroll
    for (int ni = 0; ni < 4; ++ni)
#pragma unroll
      for (int r = 0; r < 4; ++r) {
        const float v = acc[ni][r];
        const float xc = fminf(fmaxf(v, -4.97f), 4.97f);
        const float x2 = xc * xc;
        const float p = fmaf(x2, fmaf(x2, fmaf(x2, 1.0f, 378.0f), 17325.0f), 135135.0f) * xc;
        const float q = fmaf(x2, fmaf(x2, fmaf(x2, 28.0f, 3150.0f), 62370.0f), 135135.0f);
        const float th = p * __builtin_amdgcn_rcpf(q);
        const int hrow = lhi * 4 + r;
        const int fw = ((hrow & 7) ^ ((hrow >> 3) << 1)) << 4;
        *(_Float16*)(wb + hrow * 1024 +
                     (((col0 + ni * 16 + l15) * 2) ^ fw)) = (_Float16)th;
      }
    asm volatile("s_waitcnt lgkmcnt(0)" ::: "memory");
    __builtin_amdgcn_s_barrier();
    __builtin_amdgcn_sched_barrier(0);
#pragma unroll
    for (int q = 0; q < 2; ++q) {
      const int hrow = wv * 2 + q;
      const int fw = ((hrow & 7) ^ ((hrow >> 3) << 1)) << 4;
      f16x8 hv = *(const f16x8*)(wb + hrow * 1024 + ((lane * 16) ^ fw));
      f32x4 lo, hi;
      lo[0] = (float)hv[0]; lo[1] = (float)hv[1]; lo[2] = (float)hv[2]; lo[3] = (float)hv[3];
      hi[0] = (float)hv[4]; hi[1] = (float)hv[5]; hi[2] = (float)hv[6]; hi[3] = (float)hv[7];
      float* dst = hout + (size_t)t * (BB * HH) + (size_t)(row0 + hrow) * HH + lane * 8;
      *(f32x4*)dst = lo;
      *(f32x4*)(dst + 4) = hi;
      if (t == TT - 1) {
        float* fdst = hout + (size_t)TT * (BB * HH) + (size_t)(row0 + hrow) * HH + lane * 8;
        *(f32x4*)fdst = lo;
        *(f32x4*)(fdst + 4) = hi;
      }
    }
  }
}

extern "C" void kernel_launch(void* const* d_in, const int* in_sizes, int n_in,
                              void* d_out, int out_size, void* d_ws, size_t ws_size,
                              hipStream_t stream) {
  (void)in_sizes; (void)n_in; (void)out_size;
  const float* x    = (const float*)d_in[0];
  const float* w_ih = (const float*)d_in[1];
  const float* w_hh = (const float*)d_in[2];
  const float* b    = (const float*)d_in[3];
  float* out = (float*)d_out;
  const size_t need = (size_t)TT * HH * BB * sizeof(_Float16);  // 64 MB fp16 xw
  if (ws_size >= need) {
    _Float16* xwbuf = (_Float16*)d_ws;
    xw_gemm_f16<<<dim3(2048), dim3(256), 0, stream>>>(x, w_ih, b, xwbuf);
    rnn_rec_f16<<<dim3(NBLK), dim3(512), 0, stream>>>(w_hh, xwbuf, out);
  } else {
    xw_gemm_f32<<<dim3(2048), dim3(256), 0, stream>>>(x, w_ih, b, out);
    rnn_rec_f32<<<dim3(8), dim3(512), 0, stream>>>(w_hh, out, out);
  }
}

// Round 13
// 957.127 us; speedup vs baseline: 1.1334x; 1.1334x over previous
//
#include <hip/hip_runtime.h>

typedef _Float16 f16x8 __attribute__((ext_vector_type(8)));
typedef _Float16 f16x4 __attribute__((ext_vector_type(4)));
typedef float f32x4 __attribute__((ext_vector_type(4)));

#define TT 512
#define BB 128
#define II 512
#define HH 512
#define NBLK 32   // phase-2 blocks; 4 batch rows each

__device__ __forceinline__ f16x8 cvt8(f32x4 a, f32x4 b) {
  f16x8 r;
  r[0] = (_Float16)a[0]; r[1] = (_Float16)a[1];
  r[2] = (_Float16)a[2]; r[3] = (_Float16)a[3];
  r[4] = (_Float16)b[0]; r[5] = (_Float16)b[1];
  r[6] = (_Float16)b[2]; r[7] = (_Float16)b[3];
  return r;
}

// ============================ FAST PATH (ws >= 64 MB) ============================
// Phase 1: xw = x @ W_ih^T + b, fp16, BLOCK-MAJOR layout [T][NBLK][H][4]
// (element ((t*32+blk)*512+h)*4 + b_local, blk = batch>>2): each phase-2
// block's per-step slab is 4 KB contiguous (fixed FETCH 270->45 MB in r7).
__global__ __launch_bounds__(256) void xw_gemm_f16(
    const float* __restrict__ X, const float* __restrict__ Wih,
    const float* __restrict__ bias, _Float16* __restrict__ out) {
  __shared__ _Float16 As[128][40];
  __shared__ _Float16 Bs[128][40];
  const int tid = threadIdx.x;
  const int lane = tid & 63, wv = tid >> 6;
  const int l15 = lane & 15, lhi = lane >> 4;
  const int ntile = blockIdx.x & 3;
  const int mtile = blockIdx.x >> 2;   // == timestep t
  const int M0 = mtile * 128, N0 = ntile * 128;
  const int wm = (wv & 1) * 64, wn = (wv >> 1) * 64;

  f32x4 acc[4][4];
#pragma unroll
  for (int ni = 0; ni < 4; ++ni) {
    const float bv = bias[N0 + wn + ni * 16 + l15];
#pragma unroll
    for (int mi = 0; mi < 4; ++mi) {
      acc[mi][ni][0] = bv; acc[mi][ni][1] = bv;
      acc[mi][ni][2] = bv; acc[mi][ni][3] = bv;
    }
  }
  const int srow = tid >> 1;
  const int shalf = (tid & 1) * 16;

  for (int k0 = 0; k0 < II; k0 += 32) {
    const float* ax = X + (size_t)(M0 + srow) * II + k0 + shalf;
    const float* bx = Wih + (size_t)(N0 + srow) * II + k0 + shalf;
    f32x4 a0 = *(const f32x4*)ax,       a1 = *(const f32x4*)(ax + 4);
    f32x4 a2 = *(const f32x4*)(ax + 8), a3 = *(const f32x4*)(ax + 12);
    f32x4 b0 = *(const f32x4*)bx,       b1 = *(const f32x4*)(bx + 4);
    f32x4 b2 = *(const f32x4*)(bx + 8), b3 = *(const f32x4*)(bx + 12);
    *(f16x8*)&As[srow][shalf]     = cvt8(a0, a1);
    *(f16x8*)&As[srow][shalf + 8] = cvt8(a2, a3);
    *(f16x8*)&Bs[srow][shalf]     = cvt8(b0, b1);
    *(f16x8*)&Bs[srow][shalf + 8] = cvt8(b2, b3);
    __syncthreads();
    f16x8 af[4], bf[4];
#pragma unroll
    for (int mi = 0; mi < 4; ++mi) af[mi] = *(const f16x8*)&As[wm + mi * 16 + l15][lhi * 8];
#pragma unroll
    for (int ni = 0; ni < 4; ++ni) bf[ni] = *(const f16x8*)&Bs[wn + ni * 16 + l15][lhi * 8];
#pragma unroll
    for (int mi = 0; mi < 4; ++mi)
#pragma unroll
      for (int ni = 0; ni < 4; ++ni)
        acc[mi][ni] = __builtin_amdgcn_mfma_f32_16x16x32_f16(af[mi], bf[ni], acc[mi][ni], 0, 0, 0);
    __syncthreads();
  }
  // epilogue: block-major fp16. bb is 4-aligned -> b_local == 0 always.
#pragma unroll
  for (int mi = 0; mi < 4; ++mi)
#pragma unroll
    for (int ni = 0; ni < 4; ++ni) {
      const int n = N0 + wn + ni * 16 + l15;
      const int bb = wm + mi * 16 + lhi * 4;
      f16x4 hv;
      hv[0] = (_Float16)acc[mi][ni][0]; hv[1] = (_Float16)acc[mi][ni][1];
      hv[2] = (_Float16)acc[mi][ni][2]; hv[3] = (_Float16)acc[mi][ni][3];
      *(f16x4*)&out[(((size_t)mtile * NBLK + (bb >> 2)) * HH + n) * 4] = hv;
    }
}

// Phase 2: h_t = tanh(xw_t + h_{t-1} @ W_hh^T), ROW-REPLICATED MFMA.
// 32 blocks x 4 batch rows, 512 threads = 8 waves (2/SIMD), wave owns 64 cols.
// EXACT r11 structure (best measured: 883 us) + ONE isolated delta:
// s_setprio(1) around the MFMA cluster (T5) -- per-step wave role-split
// (MFMA phase vs tanh/store phase) gives the CU scheduler something to
// arbitrate; barrier skew bounds the effect but downside is ~-1.5% max.
// h buffers: rotation swizzle (store h[r][col] at r*1024+((col*2+r*32)&1023)).
// W split (r8-proven): k<384 -> 48 reg frags; k>=384 -> 128 KB XOR-swz LDS.
// One barrier/step (lgkm-only drain), direct nt global stores.
__global__ __launch_bounds__(512, 2) void rnn_rec_f16(
    const float* __restrict__ Whh,
    const _Float16* __restrict__ xw,
    float* __restrict__ hout) {
  __shared__ char lds[139264];
  char* wbase = lds;            // [512 rows][256 B] swizzled fp16, k-local 0..127
  char* hb0 = lds + 131072;     // h buffer A: [4 rows][1024 B] fp16, rotation swz
  char* hb1 = lds + 135168;     // h buffer B
  const int tid = threadIdx.x;
  const int lane = tid & 63, wv = tid >> 6;   // wv 0..7
  const int l15 = lane & 15, lhi = lane >> 4;
  const int blk = blockIdx.x;                 // 0..31
  const int row0 = blk * 4;                   // batch rows [row0, row0+4)
  const int col0 = wv * 64;
  const int mycol = col0 + lhi * 16 + l15;    // this lane's output column

  // ---- stage W k-chunk [384,512) into swizzled LDS (fp32 -> fp16) ----
#pragma unroll
  for (int i = 0; i < 16; ++i) {
    const int u = i * 512 + tid;
    const int r = u >> 4;
    const int slot = u & 15;
    const float* src = Whh + (size_t)r * HH + 384 + slot * 8;
    *(f16x8*)(wbase + r * 256 + ((slot * 16) ^ ((r & 7) << 4))) =
        cvt8(*(const f32x4*)src, *(const f32x4*)(src + 4));
  }
  // ---- zero h buffer A rows 0..3 (h_{-1} = 0; any layout, all-zero) ----
  for (int i = tid; i < 1024; i += 512) ((unsigned int*)hb0)[i] = 0u;

  // ---- W register fragments, k in [0,384) ----
  f16x8 wreg[48];
#pragma unroll
  for (int ni = 0; ni < 4; ++ni) {
    const float* wr = Whh + (size_t)(col0 + ni * 16 + l15) * HH + lhi * 8;
#pragma unroll
    for (int kj = 0; kj < 12; ++kj) {
      const float* s = wr + kj * 32;
      wreg[ni * 12 + kj] = cvt8(*(const f32x4*)s, *(const f32x4*)(s + 4));
    }
  }

  // ---- first xw prefetch (t = 0): ONE f16x4 per lane (its own column) ----
  f16x4 pref = *(const f16x4*)&xw[((size_t)blk * HH + mycol) * 4];
  __syncthreads();

  const int arow = l15 & 3;                 // replicated A row this lane reads
  const int arot = arow * 32;               // rotation offset within row
  const int wcol2 = mycol * 2;              // byte col in h row

  for (int t = 0; t < TT; ++t) {
    char* rb = (t & 1) ? hb1 : hb0;   // read h_{t-1}
    char* wb = (t & 1) ? hb0 : hb1;   // write h_t
    f32x4 acc[4];
#pragma unroll
    for (int ni = 0; ni < 4; ++ni) {
      acc[ni][0] = 0.0f; acc[ni][1] = 0.0f; acc[ni][2] = 0.0f; acc[ni][3] = 0.0f;
    }
    const f16x4 myxw = pref;
    // prefetch xw[t+1] under this step's MFMAs
    if (t + 1 < TT) {
      const size_t base = ((size_t)(t + 1) * NBLK + blk) * HH;
      pref = *(const f16x4*)&xw[(base + mycol) * 4];
    }
    // ---- h @ W^T: 12 register k-frags + 4 LDS k-frags ----
    __builtin_amdgcn_s_setprio(1);
#pragma unroll
    for (int kj = 0; kj < 16; ++kj) {
      f16x8 af = *(const f16x8*)(rb + arow * 1024 + ((kj * 64 + lhi * 16 + arot) & 1023));
      if (kj < 12) {
#pragma unroll
        for (int ni = 0; ni < 4; ++ni)
          acc[ni] = __builtin_amdgcn_mfma_f32_16x16x32_f16(af, wreg[ni * 12 + kj], acc[ni], 0, 0, 0);
      } else {
#pragma unroll
        for (int ni = 0; ni < 4; ++ni) {
          const int wrow = col0 + ni * 16 + l15;
          f16x8 bf = *(const f16x8*)(wbase + wrow * 256 +
                        ((((kj - 12) * 32 + lhi * 8) * 2) ^ ((wrow & 7) << 4)));
          acc[ni] = __builtin_amdgcn_mfma_f32_16x16x32_f16(af, bf, acc[ni], 0, 0, 0);
        }
      }
    }
    __builtin_amdgcn_s_setprio(0);
    // ---- tanh on ni == lhi (4 values/lane) -> LDS h_t + DIRECT global store
    float th4[4];
#pragma unroll
    for (int r = 0; r < 4; ++r) {
      const float s = (lhi == 0) ? acc[0][r]
                    : (lhi == 1) ? acc[1][r]
                    : (lhi == 2) ? acc[2][r]
                    :              acc[3][r];
      const float v = s + (float)myxw[r];
      const float xc = fminf(fmaxf(v, -4.97f), 4.97f);
      const float x2 = xc * xc;
      const float p = fmaf(x2, fmaf(x2, fmaf(x2, 1.0f, 378.0f), 17325.0f), 135135.0f) * xc;
      const float q = fmaf(x2, fmaf(x2, fmaf(x2, 28.0f, 3150.0f), 62370.0f), 135135.0f);
      const float th = p * __builtin_amdgcn_rcpf(q);
      th4[r] = th;
      *(_Float16*)(wb + r * 1024 + ((wcol2 + r * 32) & 1023)) = (_Float16)th;
    }
    // coalesced direct stores: per r, wave's 64 lanes cover 64 consecutive cols
    {
      float* dst = hout + (size_t)t * (BB * HH) + (size_t)row0 * HH + mycol;
#pragma unroll
      for (int r = 0; r < 4; ++r)
        __builtin_nontemporal_store(th4[r], dst + (size_t)r * HH);
      if (t == TT - 1) {
        float* fdst = hout + (size_t)TT * (BB * HH) + (size_t)row0 * HH + mycol;
#pragma unroll
        for (int r = 0; r < 4; ++r)
          __builtin_nontemporal_store(th4[r], fdst + (size_t)r * HH);
      }
    }
    // single barrier per step (lgkm-only drain; globals stay in flight)
    asm volatile("s_waitcnt lgkmcnt(0)" ::: "memory");
    __builtin_amdgcn_s_barrier();
    __builtin_amdgcn_sched_barrier(0);
  }
}

// ====================== FALLBACK (ws too small; round-3/5 validated path) ======================
__global__ __launch_bounds__(256) void xw_gemm_f32(
    const float* __restrict__ X, const float* __restrict__ Wih,
    const float* __restrict__ bias, float* __restrict__ out) {
  __shared__ _Float16 As[128][40];
  __shared__ _Float16 Bs[128][40];
  const int tid = threadIdx.x;
  const int lane = tid & 63, wv = tid >> 6;
  const int l15 = lane & 15, lhi = lane >> 4;
  const int ntile = blockIdx.x & 3;
  const int mtile = blockIdx.x >> 2;
  const int M0 = mtile * 128, N0 = ntile * 128;
  const int wm = (wv & 1) * 64, wn = (wv >> 1) * 64;
  f32x4 acc[4][4];
#pragma unroll
  for (int ni = 0; ni < 4; ++ni) {
    const float bv = bias[N0 + wn + ni * 16 + l15];
#pragma unroll
    for (int mi = 0; mi < 4; ++mi) {
      acc[mi][ni][0] = bv; acc[mi][ni][1] = bv;
      acc[mi][ni][2] = bv; acc[mi][ni][3] = bv;
    }
  }
  const int srow = tid >> 1;
  const int shalf = (tid & 1) * 16;
  for (int k0 = 0; k0 < II; k0 += 32) {
    const float* ax = X + (size_t)(M0 + srow) * II + k0 + shalf;
    const float* bx = Wih + (size_t)(N0 + srow) * II + k0 + shalf;
    f32x4 a0 = *(const f32x4*)ax,       a1 = *(const f32x4*)(ax + 4);
    f32x4 a2 = *(const f32x4*)(ax + 8), a3 = *(const f32x4*)(ax + 12);
    f32x4 b0 = *(const f32x4*)bx,       b1 = *(const f32x4*)(bx + 4);
    f32x4 b2 = *(const f32x4*)(bx + 8), b3 = *(const f32x4*)(bx + 12);
    *(f16x8*)&As[srow][shalf]     = cvt8(a0, a1);
    *(f16x8*)&As[srow][shalf + 8] = cvt8(a2, a3);
    *(f16x8*)&Bs[srow][shalf]     = cvt8(b0, b1);
    *(f16x8*)&Bs[srow][shalf + 8] = cvt8(b2, b3);
    __syncthreads();
    f16x8 af[4], bf[4];
#pragma unroll
    for (int mi = 0; mi < 4; ++mi) af[mi] = *(const f16x8*)&As[wm + mi * 16 + l15][lhi * 8];
#pragma unroll
    for (int ni = 0; ni < 4; ++ni) bf[ni] = *(const f16x8*)&Bs[wn + ni * 16 + l15][lhi * 8];
#pragma unroll
    for (int mi = 0; mi < 4; ++mi)
#pragma unroll
      for (int ni = 0; ni < 4; ++ni)
        acc[mi][ni] = __builtin_amdgcn_mfma_f32_16x16x32_f16(af[mi], bf[ni], acc[mi][ni], 0, 0, 0);
    __syncthreads();
  }
#pragma unroll
  for (int mi = 0; mi < 4; ++mi)
#pragma unroll
    for (int ni = 0; ni < 4; ++ni) {
      const size_t rbase = (size_t)(M0 + wm + mi * 16 + lhi * 4) * HH + N0 + wn + ni * 16 + l15;
#pragma unroll
      for (int r = 0; r < 4; ++r) out[rbase + (size_t)r * HH] = acc[mi][ni][r];
    }
}

__global__ __launch_bounds__(512, 2) void rnn_rec_f32(
    const float* __restrict__ Whh,
    const float* __restrict__ xw,
    float* __restrict__ hout) {
  __shared__ char lds[163840];
  char* wbase = lds;
  char* hb0 = lds + 131072;
  char* hb1 = lds + 147456;
  const int tid = threadIdx.x;
  const int lane = tid & 63, wv = tid >> 6;
  const int l15 = lane & 15, lhi = lane >> 4;
  const int row0 = blockIdx.x * 16;
  const int col0 = wv * 64;
#pragma unroll
  for (int i = 0; i < 16; ++i) {
    const int u = i * 512 + tid;
    const int r = u >> 4;
    const int slot = u & 15;
    const float* src = Whh + (size_t)r * HH + 384 + slot * 8;
    *(f16x8*)(wbase + r * 256 + ((slot * 16) ^ ((r & 7) << 4))) =
        cvt8(*(const f32x4*)src, *(const f32x4*)(src + 4));
  }
  for (int i = tid; i < 4096; i += 512) ((unsigned int*)hb0)[i] = 0u;
  f16x8 wreg[48];
#pragma unroll
  for (int ni = 0; ni < 4; ++ni) {
    const float* wr = Whh + (size_t)(col0 + ni * 16 + l15) * HH + lhi * 8;
#pragma unroll
    for (int kj = 0; kj < 12; ++kj) {
      const float* s = wr + kj * 32;
      wreg[ni * 12 + kj] = cvt8(*(const f32x4*)s, *(const f32x4*)(s + 4));
    }
  }
  f32x4 pref[4];
  {
    const size_t base0 = (size_t)(row0 + lhi * 4) * HH + col0 + l15;
#pragma unroll
    for (int ni = 0; ni < 4; ++ni)
#pragma unroll
      for (int r = 0; r < 4; ++r)
        pref[ni][r] = xw[base0 + (size_t)r * HH + ni * 16];
  }
  __syncthreads();
  const int fa = ((l15 & 7) ^ ((l15 >> 3) << 1)) << 4;
  for (int t = 0; t < TT; ++t) {
    char* rb = (t & 1) ? hb1 : hb0;
    char* wb = (t & 1) ? hb0 : hb1;
    f32x4 acc[4];
#pragma unroll
    for (int ni = 0; ni < 4; ++ni) acc[ni] = pref[ni];
    if (t + 1 < TT) {
      const size_t base = (size_t)(t + 1) * (BB * HH) + (size_t)(row0 + lhi * 4) * HH + col0 + l15;
#pragma unroll
      for (int ni = 0; ni < 4; ++ni)
#pragma unroll
        for (int r = 0; r < 4; ++r)
          pref[ni][r] = xw[base + (size_t)r * HH + ni * 16];
    }
#pragma unroll
    for (int kj = 0; kj < 12; ++kj) {
      f16x8 af = *(const f16x8*)(rb + l15 * 1024 + ((kj * 64 + lhi * 16) ^ fa));
#pragma unroll
      for (int ni = 0; ni < 4; ++ni)
        acc[ni] = __builtin_amdgcn_mfma_f32_16x16x32_f16(af, wreg[ni * 12 + kj], acc[ni], 0, 0, 0);
    }
#pragma unroll
    for (int kj = 12; kj < 16; ++kj) {
      f16x8 af = *(const f16x8*)(rb + l15 * 1024 + ((kj * 64 + lhi * 16) ^ fa));
#pragma unroll
      for (int ni = 0; ni < 4; ++ni) {
        const int wrow = col0 + ni * 16 + l15;
        f16x8 bf = *(const f16x8*)(wbase + wrow * 256 +
                      ((((kj - 12) * 32 + lhi * 8) * 2) ^ ((wrow & 7) << 4)));
        acc[ni] = __builtin_amdgcn_mfma_f32_16x16x32_f16(af, bf, acc[ni], 0, 0, 0);
      }
    }
#pragma unroll
    for (int ni = 0; ni < 4; ++ni)
#pragma unroll
      for (int r = 0; r < 4; ++r) {
        const float v = acc[ni][r];
        const float xc = fminf(fmaxf(v, -4.97f), 4.97f);
        const float x2 = xc * xc;
        const float p = fmaf(x2, fmaf(x2, fmaf(x2, 1.0f, 378.0f), 17325.0f), 135135.0f) * xc;
        const float q = fmaf(x2, fmaf(x2, fmaf(x2, 28.0f, 3150.0f), 62370.0f), 135135.0f);
        const float th = p * __builtin_amdgcn_rcpf(q);
        const int hrow = lhi * 4 + r;
        const int fw = ((hrow & 7) ^ ((hrow >> 3) << 1)) << 4;
        *(_Float16*)(wb + hrow * 1024 +
                     (((col0 + ni * 16 + l15) * 2) ^ fw)) = (_Float16)th;
      }
    asm volatile("s_waitcnt lgkmcnt(0)" ::: "memory");
    __builtin_amdgcn_s_barrier();
    __builtin_amdgcn_sched_barrier(0);
#pragma unroll
    for (int q = 0; q < 2; ++q) {
      const int hrow = wv * 2 + q;
      const int fw = ((hrow & 7) ^ ((hrow >> 3) << 1)) << 4;
      f16x8 hv = *(const f16x8*)(wb + hrow * 1024 + ((lane * 16) ^ fw));
      f32x4 lo, hi;
      lo[0] = (float)hv[0]; lo[1] = (float)hv[1]; lo[2] = (float)hv[2]; lo[3] = (float)hv[3];
      hi[0] = (float)hv[4]; hi[1] = (float)hv[5]; hi[2] = (float)hv[6]; hi[3] = (float)hv[7];
      float* dst = hout + (size_t)t * (BB * HH) + (size_t)(row0 + hrow) * HH + lane * 8;
      *(f32x4*)dst = lo;
      *(f32x4*)(dst + 4) = hi;
      if (t == TT - 1) {
        float* fdst = hout + (size_t)TT * (BB * HH) + (size_t)(row0 + hrow) * HH + lane * 8;
        *(f32x4*)fdst = lo;
        *(f32x4*)(fdst + 4) = hi;
      }
    }
  }
}

extern "C" void kernel_launch(void* const* d_in, const int* in_sizes, int n_in,
                              void* d_out, int out_size, void* d_ws, size_t ws_size,
                              hipStream_t stream) {
  (void)in_sizes; (void)n_in; (void)out_size;
  const float* x    = (const float*)d_in[0];
  const float* w_ih = (const float*)d_in[1];
  const float* w_hh = (const float*)d_in[2];
  const float* b    = (const float*)d_in[3];
  float* out = (float*)d_out;
  const size_t need = (size_t)TT * HH * BB * sizeof(_Float16);  // 64 MB fp16 xw
  if (ws_size >= need) {
    _Float16* xwbuf = (_Float16*)d_ws;
    xw_gemm_f16<<<dim3(2048), dim3(256), 0, stream>>>(x, w_ih, b, xwbuf);
    rnn_rec_f16<<<dim3(NBLK), dim3(512), 0, stream>>>(w_hh, xwbuf, out);
  } else {
    xw_gemm_f32<<<dim3(2048), dim3(256), 0, stream>>>(x, w_ih, b, out);
    rnn_rec_f32<<<dim3(8), dim3(512), 0, stream>>>(w_hh, out, out);
  }
}